// Round 11
// baseline (449.596 us; speedup 1.0000x reference)
//
#include <hip/hip_runtime.h>

typedef __bf16 bf16_t;
typedef __bf16 bf16x4 __attribute__((ext_vector_type(4)));
typedef __bf16 bf16x8 __attribute__((ext_vector_type(8)));
typedef float f32x4 __attribute__((ext_vector_type(4)));

#define LXS 264  // padded LDS row stride (kA only)

// ============ prep: pack weights into bf16 MFMA fragment-major layout ============
// frag for (nt, kt): lane l, elem j -> W[k][n], k = kt*32 + (l>>4)*8 + j, n = nt*16 + (l&15)
__global__ __launch_bounds__(256) void k_prep(
    const float* __restrict__ Wg, const float* __restrict__ Wo,
    const float* __restrict__ Wk, const float* __restrict__ Wv,
    bf16_t* __restrict__ WgP, bf16_t* __restrict__ WoP, bf16_t* __restrict__ WKVP)
{
    int id = blockIdx.x * 256 + threadIdx.x;
    if (id < 65536) {
        int j = id & 7, l = (id >> 3) & 63, kt = (id >> 9) & 7, nt = id >> 12;
        int k = kt * 32 + (l >> 4) * 8 + j;
        int n = nt * 16 + (l & 15);
        WgP[id] = (bf16_t)Wg[k * 256 + n];
    } else if (id < 131072) {
        int t = id - 65536;
        int j = t & 7, l = (t >> 3) & 63, kt = (t >> 9) & 7, nt = t >> 12;
        int k = kt * 32 + (l >> 4) * 8 + j;
        int n = nt * 16 + (l & 15);
        WoP[t] = (bf16_t)Wo[k * 256 + n];
    } else if (id < 147456) {
        int t = id - 131072;
        int j = t & 7, l = (t >> 3) & 63, kt = (t >> 9) & 7, nt = t >> 12;  // nt 0..3
        int k = kt * 32 + (l >> 4) * 8 + j;
        int n = nt * 16 + (l & 15);
        WKVP[t] = (bf16_t)(n < 32 ? Wk[k * 32 + n] : Wv[k * 32 + (n - 32)]);
    }
}

// ============ kA: LN -> lx (LDS); K|V GEMM -> kv; gate GEMM + sigmoid -> Gim (i-major, bf16);
//               fused masked column-partials for Q-pool. x_ln never hits global. ====
// Gim layout: row (i*512 + s), 256 cols. kA block (i, schunk) writes 64 CONTIGUOUS Gim rows.
__global__ __launch_bounds__(256) void kA(
    const float* __restrict__ msa, const float* __restrict__ mask,
    const float* __restrict__ gamma, const float* __restrict__ beta,
    const float* __restrict__ bg,
    bf16_t* __restrict__ Gim, bf16_t* __restrict__ kv,
    const bf16_t* __restrict__ WKVP, const bf16_t* __restrict__ WgP,
    float* __restrict__ Qpart, float* __restrict__ Qcnt)
{
    __shared__ __align__(16) bf16_t lx[64 * LXS];
    __shared__ float pp[4][256];
    __shared__ float cw[4];
    int tid = threadIdx.x;
    int lane = tid & 63, w = tid >> 6;
    int l15 = lane & 15, l4 = lane >> 4;
    int i = blockIdx.x & 511;
    int schunk = blockIdx.x >> 9;
    int s0 = schunk * 64;

    float4 g4 = ((const float4*)gamma)[lane];
    float4 b4 = ((const float4*)beta)[lane];

    // preload the wave's 8 KV-weight fragments (32 VGPR)
    bf16x8 bfr[8];
    #pragma unroll
    for (int kt = 0; kt < 8; ++kt)
        bfr[kt] = *(const bf16x8*)(WKVP + ((w * 8 + kt) * 64 + lane) * 8);

    float p0 = 0, p1 = 0, p2 = 0, p3 = 0, pc = 0;
    for (int t = 0; t < 16; ++t) {
        int rl = w * 16 + t;
        size_t r = (size_t)(s0 + rl) * 512 + i;
        float4 x = ((const float4*)(msa + r * 256))[lane];
        float mv = mask[r];
        float s  = x.x + x.y + x.z + x.w;
        float ss = x.x*x.x + x.y*x.y + x.z*x.z + x.w*x.w;
        #pragma unroll
        for (int m = 32; m; m >>= 1) { s += __shfl_xor(s, m, 64); ss += __shfl_xor(ss, m, 64); }
        float mu = s * (1.0f / 256.0f);
        float var = ss * (1.0f / 256.0f) - mu * mu;
        float rs = rsqrtf(var + 1e-5f);
        float4 y;
        y.x = (x.x - mu) * rs * g4.x + b4.x;
        y.y = (x.y - mu) * rs * g4.y + b4.y;
        y.z = (x.z - mu) * rs * g4.z + b4.z;
        y.w = (x.w - mu) * rs * g4.w + b4.w;
        bf16x4 xv;
        xv[0] = (bf16_t)y.x; xv[1] = (bf16_t)y.y; xv[2] = (bf16_t)y.z; xv[3] = (bf16_t)y.w;
        *(bf16x4*)(lx + rl * LXS + lane * 4) = xv;
        p0 += mv * y.x; p1 += mv * y.y; p2 += mv * y.z; p3 += mv * y.w;
        pc += mv;
    }
    *(float4*)&pp[w][lane * 4] = (float4){p0, p1, p2, p3};
    if (lane == 0) cw[w] = pc;
    __syncthreads();

    // Q-pool partials
    {
        float qs = pp[0][tid] + pp[1][tid] + pp[2][tid] + pp[3][tid];
        Qpart[((size_t)schunk * 512 + i) * 256 + tid] = qs;
        if (tid == 0) Qcnt[schunk * 512 + i] = cw[0] + cw[1] + cw[2] + cw[3];
    }

    // ---- KV GEMM (swapped): acc[rt] j -> row rt*16+l15, col w*16 + l4*4 + j ----
    {
        f32x4 acc[4];
        #pragma unroll
        for (int rt = 0; rt < 4; ++rt) acc[rt] = (f32x4){0.f, 0.f, 0.f, 0.f};
        #pragma unroll
        for (int kt = 0; kt < 8; ++kt) {
            #pragma unroll
            for (int rt = 0; rt < 4; ++rt) {
                bf16x8 a = *(bf16x8*)(lx + (rt * 16 + l15) * LXS + kt * 32 + l4 * 8);
                acc[rt] = __builtin_amdgcn_mfma_f32_16x16x32_bf16(bfr[kt], a, acc[rt], 0, 0, 0);
            }
        }
        #pragma unroll
        for (int rt = 0; rt < 4; ++rt) {
            int row = rt * 16 + l15;
            size_t r = (size_t)(s0 + row) * 512 + i;
            bf16x4 kvv;
            #pragma unroll
            for (int j = 0; j < 4; ++j) kvv[j] = (bf16_t)acc[rt][j];
            *(bf16x4*)(kv + r * 64 + w * 16 + l4 * 4) = kvv;
        }
    }

    // ---- gate GEMM: wave w -> cols [w*64, +64) as 2 ctl-pairs; sigmoid; store Gim (i-major) ----
    #pragma unroll
    for (int cp = 0; cp < 2; ++cp) {
        int nt0 = w * 4 + cp * 2, nt1 = nt0 + 1;
        f32x4 ga0[4], ga1[4];
        #pragma unroll
        for (int rt = 0; rt < 4; ++rt) { ga0[rt] = (f32x4){0.f,0.f,0.f,0.f}; ga1[rt] = (f32x4){0.f,0.f,0.f,0.f}; }
        bf16x8 w0 = *(const bf16x8*)(WgP + ((nt0 * 8 + 0) * 64 + lane) * 8);
        bf16x8 w1 = *(const bf16x8*)(WgP + ((nt1 * 8 + 0) * 64 + lane) * 8);
        #pragma unroll
        for (int kt = 0; kt < 8; ++kt) {
            int ktn = (kt + 1) & 7;
            bf16x8 w0n = *(const bf16x8*)(WgP + ((nt0 * 8 + ktn) * 64 + lane) * 8);
            bf16x8 w1n = *(const bf16x8*)(WgP + ((nt1 * 8 + ktn) * 64 + lane) * 8);
            bf16x8 a[4];
            #pragma unroll
            for (int rt = 0; rt < 4; ++rt)
                a[rt] = *(bf16x8*)(lx + (rt * 16 + l15) * LXS + kt * 32 + l4 * 8);
            #pragma unroll
            for (int rt = 0; rt < 4; ++rt) {
                ga0[rt] = __builtin_amdgcn_mfma_f32_16x16x32_bf16(w0, a[rt], ga0[rt], 0, 0, 0);
                ga1[rt] = __builtin_amdgcn_mfma_f32_16x16x32_bf16(w1, a[rt], ga1[rt], 0, 0, 0);
            }
            w0 = w0n; w1 = w1n;
        }
        #pragma unroll
        for (int e = 0; e < 2; ++e) {
            int nt = (e == 0) ? nt0 : nt1;
            int c4 = nt * 16 + l4 * 4;
            float4 bg4 = *(const float4*)(bg + c4);
            #pragma unroll
            for (int rt = 0; rt < 4; ++rt) {
                f32x4 t4 = (e == 0) ? ga0[rt] : ga1[rt];
                int row = rt * 16 + l15;
                size_t grow = ((size_t)i << 9) + s0 + row;   // i-major: contiguous rows per block
                bf16x4 gv;
                gv[0] = (bf16_t)(1.0f / (1.0f + __expf(-(t4[0] + bg4.x))));
                gv[1] = (bf16_t)(1.0f / (1.0f + __expf(-(t4[1] + bg4.y))));
                gv[2] = (bf16_t)(1.0f / (1.0f + __expf(-(t4[2] + bg4.z))));
                gv[3] = (bf16_t)(1.0f / (1.0f + __expf(-(t4[3] + bg4.w))));
                *(bf16x4*)(Gim + grow * 256 + c4) = gv;
            }
        }
    }
}

// ============ kB: finish Q-pool: sum 8 partials, tiny GEMM with Wq ============
__global__ __launch_bounds__(256) void kB(
    const float* __restrict__ Qpart, const float* __restrict__ Qcnt,
    const float* __restrict__ Wq, float* __restrict__ Q)
{
    int i = blockIdx.x, tid = threadIdx.x;
    __shared__ float xs[256];
    float s = 0;
    #pragma unroll
    for (int ch = 0; ch < 8; ++ch) s += Qpart[((size_t)ch * 512 + i) * 256 + tid];
    xs[tid] = s;
    float cnt = 0;
    #pragma unroll
    for (int ch = 0; ch < 8; ++ch) cnt += Qcnt[ch * 512 + i];
    __syncthreads();
    float scale = 1.0f / (fmaxf(cnt, 1.0f) * 5.656854249492381f);  // sqrt(32)
    float q = 0;
    for (int c = 0; c < 256; ++c) q += xs[c] * Wq[c * 256 + tid];
    Q[i * 256 + tid] = q * scale;
}

// ============ kC: per-column-i attention: scores -> softmax(t) -> weighted = attn @ V ============
__global__ __launch_bounds__(256) void kC(
    const bf16_t* __restrict__ kv, const float* __restrict__ mask,
    const float* __restrict__ Q, float* __restrict__ wout)
{
    int i = blockIdx.x, tid = threadIdx.x;
    __shared__ __align__(16) bf16_t kbuf[512 * 32];
    __shared__ float sc[512 * 8];
    __shared__ float qq[256];
    __shared__ float mk[512];
    __shared__ float rcp[8];

    qq[tid] = Q[i * 256 + tid];
    mk[tid] = mask[tid * 512 + i];
    mk[tid + 256] = mask[(tid + 256) * 512 + i];

    for (int it = 0; it < 8; ++it) {
        int idx = it * 256 + tid; int t = idx >> 2; int q = idx & 3;
        ((uint4*)kbuf)[t * 4 + q] = ((const uint4*)kv)[((size_t)t * 512 + i) * 8 + q];
    }
    __syncthreads();

    for (int it = 0; it < 16; ++it) {
        int idx = it * 256 + tid; int t = idx >> 3; int h = idx & 7;
        float a = 0;
        #pragma unroll 8
        for (int d = 0; d < 32; ++d) a += qq[h * 32 + d] * (float)kbuf[t * 32 + d];
        sc[t * 8 + h] = a - (1.0f - mk[t]) * 1e9f;
    }
    __syncthreads();

    {
        int h = tid >> 5, l = tid & 31;
        float m = -1e30f;
        for (int k = 0; k < 16; ++k) m = fmaxf(m, sc[(l + 32 * k) * 8 + h]);
        #pragma unroll
        for (int off = 16; off; off >>= 1) m = fmaxf(m, __shfl_xor(m, off, 64));
        float s = 0;
        for (int k = 0; k < 16; ++k) {
            int idx = (l + 32 * k) * 8 + h;
            float p = __expf(sc[idx] - m);
            sc[idx] = p; s += p;
        }
        #pragma unroll
        for (int off = 16; off; off >>= 1) s += __shfl_xor(s, off, 64);
        if (l == 0) rcp[h] = 1.0f / s;
    }
    for (int it = 0; it < 8; ++it) {
        int idx = it * 256 + tid; int t = idx >> 2; int q = idx & 3;
        ((uint4*)kbuf)[t * 4 + q] = ((const uint4*)kv)[((size_t)t * 512 + i) * 8 + 4 + q];
    }
    __syncthreads();

    {
        int h = tid >> 5, d = tid & 31;
        float acc = 0;
        for (int t = 0; t < 512; ++t) acc += sc[t * 8 + h] * (float)kbuf[t * 32 + d];
        wout[i * 256 + tid] = acc * rcp[h];
    }
}

// ============ kD: single GEMM, ZERO barriers, ZERO LDS. Wave = 64 rows x 64 cols (q quarter),
//   processed as 2 half-passes of 32 rows: G-frags direct from Gim (scattered 512B rows,
//   L3-resident) ⊙ weighted -> gt regs -> GEMM (Wo 2-deep) -> NT stores. ====
__global__ __launch_bounds__(256, 3) void kD(
    const bf16_t* __restrict__ Gim, const bf16_t* __restrict__ WoP,
    const float* __restrict__ bo, const float* __restrict__ weighted,
    const float* __restrict__ mask, float* __restrict__ out)
{
    int tid = threadIdx.x;
    int lane = tid & 63, q = tid >> 6;
    int l15 = lane & 15, l4 = lane >> 4;
    int rowbase = blockIdx.x * 64;
    int sblk = rowbase >> 9, i0 = rowbase & 511;   // 64 consecutive rows: fixed s, consecutive i

#define LOADW(DST, KT) \
    _Pragma("unroll") \
    for (int ctl = 0; ctl < 4; ++ctl) \
        DST[ctl] = *(const bf16x8*)(WoP + ((((q * 4 + ctl) * 8 + (KT)) * 64 + lane) * 8));

#define GSTEP(BW, KT) \
    _Pragma("unroll") \
    for (int ctl = 0; ctl < 4; ++ctl) \
        _Pragma("unroll") \
        for (int rt = 0; rt < 2; ++rt) \
            acc[rt][ctl] = __builtin_amdgcn_mfma_f32_16x16x32_bf16(BW[ctl], gt[rt][KT], acc[rt][ctl], 0, 0, 0);

    #pragma unroll
    for (int rh = 0; rh < 2; ++rh) {
        // ---- build gated frags for this half's 32 rows ----
        bf16x8 gt[2][8];
        float mv[2];
        #pragma unroll
        for (int rt = 0; rt < 2; ++rt) {
            int lrow = rh * 32 + rt * 16 + l15;
            const bf16_t* gp = Gim + (((size_t)(i0 + lrow) << 9) + sblk) * 256 + l4 * 8;
            const float*  wp = weighted + (i0 + lrow) * 256 + l4 * 8;
            #pragma unroll
            for (int kt = 0; kt < 8; ++kt) {
                bf16x8 g8 = *(const bf16x8*)(gp + kt * 32);
                f32x4 w0 = *(const f32x4*)(wp + kt * 32);
                f32x4 w1 = *(const f32x4*)(wp + kt * 32 + 4);
                #pragma unroll
                for (int j = 0; j < 4; ++j) {
                    gt[rt][kt][j]     = (bf16_t)((float)g8[j]     * w0[j]);
                    gt[rt][kt][j + 4] = (bf16_t)((float)g8[j + 4] * w1[j]);
                }
            }
            mv[rt] = mask[rowbase + lrow];
        }

        // ---- GEMM: 32 rows x 64 cols, Wo streamed 2-deep ----
        f32x4 acc[2][4];
        #pragma unroll
        for (int rt = 0; rt < 2; ++rt)
            #pragma unroll
            for (int ctl = 0; ctl < 4; ++ctl) acc[rt][ctl] = (f32x4){0.f, 0.f, 0.f, 0.f};
        bf16x8 bA[4], bB[4];
        LOADW(bA, 0)
        LOADW(bB, 1)
        GSTEP(bA, 0) LOADW(bA, 2)
        GSTEP(bB, 1) LOADW(bB, 3)
        GSTEP(bA, 2) LOADW(bA, 4)
        GSTEP(bB, 3) LOADW(bB, 5)
        GSTEP(bA, 4) LOADW(bA, 6)
        GSTEP(bB, 5) LOADW(bB, 7)
        GSTEP(bA, 6)
        GSTEP(bB, 7)

        // ---- epi: + bo, * mask, NT f32x4 stores ----
        #pragma unroll
        for (int ctl = 0; ctl < 4; ++ctl) {
            int c4 = (q * 4 + ctl) * 16 + l4 * 4;
            float4 bo4 = *(const float4*)(bo + c4);
            #pragma unroll
            for (int rt = 0; rt < 2; ++rt) {
                int r = rowbase + rh * 32 + rt * 16 + l15;
                f32x4 o;
                o[0] = (acc[rt][ctl][0] + bo4.x) * mv[rt];
                o[1] = (acc[rt][ctl][1] + bo4.y) * mv[rt];
                o[2] = (acc[rt][ctl][2] + bo4.z) * mv[rt];
                o[3] = (acc[rt][ctl][3] + bo4.w) * mv[rt];
                __builtin_nontemporal_store(o, (f32x4*)(out + (size_t)r * 256 + c4));
            }
        }
    }
#undef LOADW
#undef GSTEP
}

extern "C" void kernel_launch(void* const* d_in, const int* in_sizes, int n_in,
                              void* d_out, int out_size, void* d_ws, size_t ws_size,
                              hipStream_t stream) {
    const float* msa   = (const float*)d_in[0];
    const float* mask  = (const float*)d_in[1];
    const float* gamma = (const float*)d_in[2];
    const float* beta  = (const float*)d_in[3];
    const float* Wq    = (const float*)d_in[4];
    const float* Wk    = (const float*)d_in[5];
    const float* Wv    = (const float*)d_in[6];
    const float* Wg    = (const float*)d_in[7];
    const float* bg    = (const float*)d_in[8];
    const float* Wo    = (const float*)d_in[9];
    const float* bo    = (const float*)d_in[10];
    float* out = (float*)d_out;

    char* ws = (char*)d_ws;
    bf16_t* Gim   = (bf16_t*)(ws);                     // 128 MB, i-major gate (replaces xln)
    bf16_t* kv    = (bf16_t*)(ws + 134217728);         // 32 MB
    float*  Qp    = (float*)(ws + 167772160);          // 512 KB
    float*  wgt   = (float*)(ws + 168296448);          // 512 KB
    bf16_t* WgP   = (bf16_t*)(ws + 168820736);         // 128 KB
    bf16_t* WoP   = (bf16_t*)(ws + 168951808);         // 128 KB
    bf16_t* WKVP  = (bf16_t*)(ws + 169082880);         // 32 KB
    float*  Qpart = (float*)(ws + 169115648);          // 4 MB
    float*  Qcnt  = (float*)(ws + 173309952);          // 16 KB

    k_prep<<<576, 256, 0, stream>>>(Wg, Wo, Wk, Wv, WgP, WoP, WKVP);
    kA<<<4096, 256, 0, stream>>>(msa, mask, gamma, beta, bg, Gim, kv, WKVP, WgP, Qpart, Qcnt);
    kB<<<512, 256, 0, stream>>>(Qpart, Qcnt, Wq, Qp);
    kC<<<512, 256, 0, stream>>>(kv, mask, Qp, wgt);
    kD<<<4096, 256, 0, stream>>>(Gim, WoP, bo, wgt, mask, out);
}

// Round 12
// 270.487 us; speedup vs baseline: 1.6622x; 1.6622x over previous
//
#include <hip/hip_runtime.h>

typedef __bf16 bf16_t;
typedef __bf16 bf16x4 __attribute__((ext_vector_type(4)));
typedef __bf16 bf16x8 __attribute__((ext_vector_type(8)));
typedef float f32x4 __attribute__((ext_vector_type(4)));

#define LXS 264  // padded LDS row stride (kA only)

#define GLOAD_LDS16(gsrc, ldst) \
    __builtin_amdgcn_global_load_lds((__attribute__((address_space(1))) void*)(gsrc), \
                                     (__attribute__((address_space(3))) void*)(ldst), 16, 0, 0)

// ============ prep: pack weights into bf16 MFMA fragment-major layout ============
// frag for (nt, kt): lane l, elem j -> W[k][n], k = kt*32 + (l>>4)*8 + j, n = nt*16 + (l&15)
__global__ __launch_bounds__(256) void k_prep(
    const float* __restrict__ Wg, const float* __restrict__ Wo,
    const float* __restrict__ Wk, const float* __restrict__ Wv,
    bf16_t* __restrict__ WgP, bf16_t* __restrict__ WoP, bf16_t* __restrict__ WKVP)
{
    int id = blockIdx.x * 256 + threadIdx.x;
    if (id < 65536) {
        int j = id & 7, l = (id >> 3) & 63, kt = (id >> 9) & 7, nt = id >> 12;
        int k = kt * 32 + (l >> 4) * 8 + j;
        int n = nt * 16 + (l & 15);
        WgP[id] = (bf16_t)Wg[k * 256 + n];
    } else if (id < 131072) {
        int t = id - 65536;
        int j = t & 7, l = (t >> 3) & 63, kt = (t >> 9) & 7, nt = t >> 12;
        int k = kt * 32 + (l >> 4) * 8 + j;
        int n = nt * 16 + (l & 15);
        WoP[t] = (bf16_t)Wo[k * 256 + n];
    } else if (id < 147456) {
        int t = id - 131072;
        int j = t & 7, l = (t >> 3) & 63, kt = (t >> 9) & 7, nt = t >> 12;  // nt 0..3
        int k = kt * 32 + (l >> 4) * 8 + j;
        int n = nt * 16 + (l & 15);
        WKVP[t] = (bf16_t)(n < 32 ? Wk[k * 32 + n] : Wv[k * 32 + (n - 32)]);
    }
}

// ============ kA: LN -> x_ln (bf16); K|V via MFMA (swapped operands); fused Q-pool partials ====
__global__ __launch_bounds__(256) void kA(
    const float* __restrict__ msa, const float* __restrict__ mask,
    const float* __restrict__ gamma, const float* __restrict__ beta,
    bf16_t* __restrict__ xln, bf16_t* __restrict__ kv, const bf16_t* __restrict__ WKVP,
    float* __restrict__ Qpart, float* __restrict__ Qcnt)
{
    __shared__ __align__(16) bf16_t lx[64 * LXS];
    __shared__ float pp[4][256];
    __shared__ float cw[4];
    int tid = threadIdx.x;
    int lane = tid & 63, w = tid >> 6;
    int l15 = lane & 15, l4 = lane >> 4;
    int i = blockIdx.x & 511;
    int schunk = blockIdx.x >> 9;
    int s0 = schunk * 64;

    float4 g4 = ((const float4*)gamma)[lane];
    float4 b4 = ((const float4*)beta)[lane];

    bf16x8 bfr[8];
    #pragma unroll
    for (int kt = 0; kt < 8; ++kt)
        bfr[kt] = *(const bf16x8*)(WKVP + ((w * 8 + kt) * 64 + lane) * 8);

    float p0 = 0, p1 = 0, p2 = 0, p3 = 0, pc = 0;
    for (int t = 0; t < 16; ++t) {
        int rl = w * 16 + t;
        size_t r = (size_t)(s0 + rl) * 512 + i;
        float4 x = ((const float4*)(msa + r * 256))[lane];
        float mv = mask[r];
        float s  = x.x + x.y + x.z + x.w;
        float ss = x.x*x.x + x.y*x.y + x.z*x.z + x.w*x.w;
        #pragma unroll
        for (int m = 32; m; m >>= 1) { s += __shfl_xor(s, m, 64); ss += __shfl_xor(ss, m, 64); }
        float mu = s * (1.0f / 256.0f);
        float var = ss * (1.0f / 256.0f) - mu * mu;
        float rs = rsqrtf(var + 1e-5f);
        float4 y;
        y.x = (x.x - mu) * rs * g4.x + b4.x;
        y.y = (x.y - mu) * rs * g4.y + b4.y;
        y.z = (x.z - mu) * rs * g4.z + b4.z;
        y.w = (x.w - mu) * rs * g4.w + b4.w;
        bf16x4 xv;
        xv[0] = (bf16_t)y.x; xv[1] = (bf16_t)y.y; xv[2] = (bf16_t)y.z; xv[3] = (bf16_t)y.w;
        *(bf16x4*)(xln + r * 256 + lane * 4) = xv;
        *(bf16x4*)(lx + rl * LXS + lane * 4) = xv;
        p0 += mv * y.x; p1 += mv * y.y; p2 += mv * y.z; p3 += mv * y.w;
        pc += mv;
    }
    *(float4*)&pp[w][lane * 4] = (float4){p0, p1, p2, p3};
    if (lane == 0) cw[w] = pc;
    __syncthreads();

    {
        float qs = pp[0][tid] + pp[1][tid] + pp[2][tid] + pp[3][tid];
        Qpart[((size_t)schunk * 512 + i) * 256 + tid] = qs;
        if (tid == 0) Qcnt[schunk * 512 + i] = cw[0] + cw[1] + cw[2] + cw[3];
    }

    // MFMA (swapped): acc[rt] elem j -> row = rt*16+l15 (s-local), col = w*16 + l4*4 + j
    f32x4 acc[4];
    #pragma unroll
    for (int rt = 0; rt < 4; ++rt) acc[rt] = (f32x4){0.f, 0.f, 0.f, 0.f};
    #pragma unroll
    for (int kt = 0; kt < 8; ++kt) {
        #pragma unroll
        for (int rt = 0; rt < 4; ++rt) {
            bf16x8 a = *(bf16x8*)(lx + (rt * 16 + l15) * LXS + kt * 32 + l4 * 8);
            acc[rt] = __builtin_amdgcn_mfma_f32_16x16x32_bf16(bfr[kt], a, acc[rt], 0, 0, 0);
        }
    }
    #pragma unroll
    for (int rt = 0; rt < 4; ++rt) {
        int row = rt * 16 + l15;
        size_t r = (size_t)(s0 + row) * 512 + i;
        bf16x4 kvv;
        #pragma unroll
        for (int j = 0; j < 4; ++j) kvv[j] = (bf16_t)acc[rt][j];
        *(bf16x4*)(kv + r * 64 + w * 16 + l4 * 4) = kvv;
    }
}

// ============ kB: finish Q-pool: sum 8 partials, tiny GEMM with Wq ============
__global__ __launch_bounds__(256) void kB(
    const float* __restrict__ Qpart, const float* __restrict__ Qcnt,
    const float* __restrict__ Wq, float* __restrict__ Q)
{
    int i = blockIdx.x, tid = threadIdx.x;
    __shared__ float xs[256];
    float s = 0;
    #pragma unroll
    for (int ch = 0; ch < 8; ++ch) s += Qpart[((size_t)ch * 512 + i) * 256 + tid];
    xs[tid] = s;
    float cnt = 0;
    #pragma unroll
    for (int ch = 0; ch < 8; ++ch) cnt += Qcnt[ch * 512 + i];
    __syncthreads();
    float scale = 1.0f / (fmaxf(cnt, 1.0f) * 5.656854249492381f);  // sqrt(32)
    float q = 0;
    for (int c = 0; c < 256; ++c) q += xs[c] * Wq[c * 256 + tid];
    Q[i * 256 + tid] = q * scale;
}

// ============ kC1: flash split-t attention partials. block = (i, chunk of 128 t) ============
__global__ __launch_bounds__(256) void kC1(
    const bf16_t* __restrict__ kv, const float* __restrict__ mask, const float* __restrict__ Q,
    float* __restrict__ Wp, float* __restrict__ Mp, float* __restrict__ Lp)
{
    int i = blockIdx.x & 511, ch = blockIdx.x >> 9;
    int t0 = ch * 128;
    int tid = threadIdx.x;
    __shared__ __align__(16) bf16_t kbuf[128 * 32];  // 8KB: K rows, then reused for V
    __shared__ float sc[128 * 8];
    __shared__ float qq[256];
    __shared__ float mk[128];
    __shared__ float mred[8], lred[8];

    qq[tid] = Q[i * 256 + tid];
    if (tid < 128) mk[tid] = mask[(size_t)(t0 + tid) * 512 + i];

    #pragma unroll
    for (int it = 0; it < 2; ++it) {
        int idx = it * 256 + tid; int t = idx >> 2; int q = idx & 3;
        ((uint4*)kbuf)[t * 4 + q] = ((const uint4*)kv)[((size_t)(t0 + t) * 512 + i) * 8 + q];
    }
    __syncthreads();

    #pragma unroll
    for (int it = 0; it < 4; ++it) {
        int idx = it * 256 + tid; int t = idx >> 3; int h = idx & 7;
        float a = 0;
        #pragma unroll 8
        for (int d = 0; d < 32; ++d) a += qq[h * 32 + d] * (float)kbuf[t * 32 + d];
        sc[t * 8 + h] = a - (1.0f - mk[t]) * 1e9f;
    }
    __syncthreads();

    #pragma unroll
    for (int it = 0; it < 2; ++it) {
        int idx = it * 256 + tid; int t = idx >> 2; int q = idx & 3;
        ((uint4*)kbuf)[t * 4 + q] = ((const uint4*)kv)[((size_t)(t0 + t) * 512 + i) * 8 + 4 + q];
    }
    {
        int h = tid >> 5, l = tid & 31;
        float m = -3e38f;
        #pragma unroll
        for (int k = 0; k < 4; ++k) m = fmaxf(m, sc[(l + 32 * k) * 8 + h]);
        #pragma unroll
        for (int off = 16; off; off >>= 1) m = fmaxf(m, __shfl_xor(m, off, 32));
        float s = 0;
        #pragma unroll
        for (int k = 0; k < 4; ++k) {
            int idx = (l + 32 * k) * 8 + h;
            float p = __expf(sc[idx] - m);
            sc[idx] = p; s += p;
        }
        #pragma unroll
        for (int off = 16; off; off >>= 1) s += __shfl_xor(s, off, 32);
        if (l == 0) { mred[h] = m; lred[h] = s; }
    }
    __syncthreads();

    {
        int h = tid >> 5, d = tid & 31;
        float a = 0;
        for (int t = 0; t < 128; ++t) a += sc[t * 8 + h] * (float)kbuf[t * 32 + d];
        Wp[((size_t)ch * 512 + i) * 256 + tid] = a;
    }
    if (tid < 8) {
        Mp[((size_t)ch * 512 + i) * 8 + tid] = mred[tid];
        Lp[((size_t)ch * 512 + i) * 8 + tid] = lred[tid];
    }
}

// ============ kC2: combine 4 chunk partials -> weighted [i][256] ============
__global__ __launch_bounds__(256) void kC2(
    const float* __restrict__ Wp, const float* __restrict__ Mp, const float* __restrict__ Lp,
    float* __restrict__ wgt)
{
    int i = blockIdx.x, tid = threadIdx.x;
    int h = tid >> 5;
    float m[4], l[4];
    #pragma unroll
    for (int ch = 0; ch < 4; ++ch) {
        m[ch] = Mp[((size_t)ch * 512 + i) * 8 + h];
        l[ch] = Lp[((size_t)ch * 512 + i) * 8 + h];
    }
    float M = fmaxf(fmaxf(m[0], m[1]), fmaxf(m[2], m[3]));
    float den = 0, num = 0;
    #pragma unroll
    for (int ch = 0; ch < 4; ++ch) {
        float e = __expf(m[ch] - M);
        den += l[ch] * e;
        num += Wp[((size_t)ch * 512 + i) * 256 + tid] * e;
    }
    wgt[i * 256 + tid] = num / den;
}

// ============ kD: R6 body + separate stage/gated LDS buffers (one barrier removed)
//               + issue-early Wo prefetch. 64-row tile, 64x64 wave tiles, swapped MFMA. ====
__global__ __launch_bounds__(256, 2) void kD(
    const bf16_t* __restrict__ xln, const bf16_t* __restrict__ WgP, const bf16_t* __restrict__ WoP,
    const float* __restrict__ bg, const float* __restrict__ bo,
    const float* __restrict__ weighted, const float* __restrict__ mask, float* __restrict__ out)
{
    __shared__ __align__(16) bf16_t lxs[64 * 256];  // 32 KB staged xln
    __shared__ __align__(16) bf16_t gl[64 * 256];   // 32 KB gated
    int tid = threadIdx.x;
    int lane = tid & 63, q = tid >> 6;
    int l15 = lane & 15, l4 = lane >> 4;
    int swb = l15 & 7;
    int rowbase = blockIdx.x * 64;

    // stage xln tile via global_load_lds, inverse-swizzled source
    const bf16_t* sB = xln + (size_t)rowbase * 256;
    #pragma unroll
    for (int c = 0; c < 8; ++c) {
        int idx = (c * 256 + tid) * 16;
        int row_ = idx >> 9;
        int g_ = (idx >> 4) & 31;
        GLOAD_LDS16(sB + row_ * 256 + (g_ ^ (row_ & 7)) * 8, lxs + c * 2048 + q * 512);
    }
    __syncthreads();  // barrier 1: stage complete

#define LOADW(DST, WP, KT) \
    _Pragma("unroll") \
    for (int ctl = 0; ctl < 4; ++ctl) \
        DST[ctl] = *(const bf16x8*)((WP) + ((((q * 4 + ctl) * 8 + (KT)) * 64 + lane) * 8));

#define GSTEP(BW, KT, BUF) \
    { bf16x8 a2[4]; \
      _Pragma("unroll") \
      for (int rt = 0; rt < 4; ++rt) \
          a2[rt] = *(bf16x8*)((BUF) + (rt * 16 + l15) * 256 + (((KT) * 4 + l4) ^ swb) * 8); \
      _Pragma("unroll") \
      for (int ctl = 0; ctl < 4; ++ctl) \
          _Pragma("unroll") \
          for (int rt = 0; rt < 4; ++rt) \
              acc[rt][ctl] = __builtin_amdgcn_mfma_f32_16x16x32_bf16(BW[ctl], a2[rt], acc[rt][ctl], 0, 0, 0); }

    f32x4 acc[4][4];
    bf16x8 bA[4], bB[4];

    // ---- GEMM1: T = xln @ Wg (Wg streamed 2-deep) ----
    #pragma unroll
    for (int rt = 0; rt < 4; ++rt)
        #pragma unroll
        for (int ctl = 0; ctl < 4; ++ctl) acc[rt][ctl] = (f32x4){0.f, 0.f, 0.f, 0.f};
    LOADW(bA, WgP, 0)
    LOADW(bB, WgP, 1)
    GSTEP(bA, 0, lxs) LOADW(bA, WgP, 2)
    GSTEP(bB, 1, lxs) LOADW(bB, WgP, 3)
    GSTEP(bA, 2, lxs) LOADW(bA, WgP, 4)
    GSTEP(bB, 3, lxs) LOADW(bB, WgP, 5)
    GSTEP(bA, 4, lxs) LOADW(bA, WgP, 6)
    GSTEP(bB, 5, lxs) LOADW(bB, WgP, 7)
    GSTEP(bA, 6, lxs)
    GSTEP(bB, 7, lxs)

    // issue-early: first two Wo rounds in flight across epi1 + barrier
    LOADW(bA, WoP, 0)
    LOADW(bB, WoP, 1)

    // ---- epi1: gated = sigmoid(T+bg) * weighted -> gl (bf16x4, swizzled); NO barrier needed
    //      before this (separate buffer) ----
    #pragma unroll
    for (int ctl = 0; ctl < 4; ++ctl) {
        int c4 = (q * 4 + ctl) * 16 + l4 * 4;
        float4 bg4 = *(const float4*)(bg + c4);
        int g0 = c4 >> 3, c7 = c4 & 7;
        #pragma unroll
        for (int rt = 0; rt < 4; ++rt) {
            int row = rt * 16 + l15;
            int i2 = (rowbase + row) & 511;
            float4 w4 = *(const float4*)(weighted + i2 * 256 + c4);
            f32x4 t4 = acc[rt][ctl];
            bf16x4 gv;
            gv[0] = (bf16_t)(w4.x / (1.0f + __expf(-(t4[0] + bg4.x))));
            gv[1] = (bf16_t)(w4.y / (1.0f + __expf(-(t4[1] + bg4.y))));
            gv[2] = (bf16_t)(w4.z / (1.0f + __expf(-(t4[2] + bg4.z))));
            gv[3] = (bf16_t)(w4.w / (1.0f + __expf(-(t4[3] + bg4.w))));
            *(bf16x4*)(gl + row * 256 + ((g0 ^ (row & 7)) << 3) + c7) = gv;
        }
    }
    __syncthreads();  // barrier 2: gated exchange complete

    // ---- GEMM2: out = gated @ Wo (Wo stream continues from kt=2) ----
    #pragma unroll
    for (int rt = 0; rt < 4; ++rt)
        #pragma unroll
        for (int ctl = 0; ctl < 4; ++ctl) acc[rt][ctl] = (f32x4){0.f, 0.f, 0.f, 0.f};
    GSTEP(bA, 0, gl) LOADW(bA, WoP, 2)
    GSTEP(bB, 1, gl) LOADW(bB, WoP, 3)
    GSTEP(bA, 2, gl) LOADW(bA, WoP, 4)
    GSTEP(bB, 3, gl) LOADW(bB, WoP, 5)
    GSTEP(bA, 4, gl) LOADW(bA, WoP, 6)
    GSTEP(bB, 5, gl) LOADW(bB, WoP, 7)
    GSTEP(bA, 6, gl)
    GSTEP(bB, 7, gl)

    // ---- epi2: + bo, * mask, nontemporal f32x4 stores ----
    #pragma unroll
    for (int ctl = 0; ctl < 4; ++ctl) {
        int c4 = (q * 4 + ctl) * 16 + l4 * 4;
        float4 bo4 = *(const float4*)(bo + c4);
        #pragma unroll
        for (int rt = 0; rt < 4; ++rt) {
            int r = rowbase + rt * 16 + l15;
            float mv = mask[r];
            f32x4 o;
            o[0] = (acc[rt][ctl][0] + bo4.x) * mv;
            o[1] = (acc[rt][ctl][1] + bo4.y) * mv;
            o[2] = (acc[rt][ctl][2] + bo4.z) * mv;
            o[3] = (acc[rt][ctl][3] + bo4.w) * mv;
            __builtin_nontemporal_store(o, (f32x4*)(out + (size_t)r * 256 + c4));
        }
    }
#undef LOADW
#undef GSTEP
}

extern "C" void kernel_launch(void* const* d_in, const int* in_sizes, int n_in,
                              void* d_out, int out_size, void* d_ws, size_t ws_size,
                              hipStream_t stream) {
    const float* msa   = (const float*)d_in[0];
    const float* mask  = (const float*)d_in[1];
    const float* gamma = (const float*)d_in[2];
    const float* beta  = (const float*)d_in[3];
    const float* Wq    = (const float*)d_in[4];
    const float* Wk    = (const float*)d_in[5];
    const float* Wv    = (const float*)d_in[6];
    const float* Wg    = (const float*)d_in[7];
    const float* bg    = (const float*)d_in[8];
    const float* Wo    = (const float*)d_in[9];
    const float* bo    = (const float*)d_in[10];
    float* out = (float*)d_out;

    char* ws = (char*)d_ws;
    bf16_t* xln   = (bf16_t*)(ws);                     // 128 MB
    bf16_t* kv    = (bf16_t*)(ws + 134217728);         // 32 MB
    float*  Qp    = (float*)(ws + 167772160);          // 512 KB
    float*  wgt   = (float*)(ws + 168296448);          // 512 KB
    bf16_t* WgP   = (bf16_t*)(ws + 168820736);         // 128 KB
    bf16_t* WoP   = (bf16_t*)(ws + 168951808);         // 128 KB
    bf16_t* WKVP  = (bf16_t*)(ws + 169082880);         // 32 KB
    float*  Qpart = (float*)(ws + 169115648);          // 4 MB (dead after kB; Wp reuses it)
    float*  Qcnt  = (float*)(ws + 173309952);          // 16 KB
    float*  Wp    = (float*)(ws + 169115648);          // 2 MB, overlays Qpart (kB done before kC1)
    float*  Mp    = (float*)(ws + 173326336);          // 64 KB
    float*  Lp    = (float*)(ws + 173391872);          // 64 KB

    k_prep<<<576, 256, 0, stream>>>(Wg, Wo, Wk, Wv, WgP, WoP, WKVP);
    kA<<<4096, 256, 0, stream>>>(msa, mask, gamma, beta, xln, kv, WKVP, Qpart, Qcnt);
    kB<<<512, 256, 0, stream>>>(Qpart, Qcnt, Wq, Qp);
    kC1<<<2048, 256, 0, stream>>>(kv, mask, Qp, Wp, Mp, Lp);
    kC2<<<512, 256, 0, stream>>>(Wp, Mp, Lp, wgt);
    kD<<<4096, 256, 0, stream>>>(xln, WgP, WoP, bg, bo, wgt, mask, out);
}